// Round 1
// 309.121 us; speedup vs baseline: 1.0074x; 1.0074x over previous
//
#include <hip/hip_runtime.h>

// CognitiveLorenzField: 500-step scan over DIM=65536 vectors.
// Exact 2D-subspace reduction: vL_t = p_t*vL0, vJ_t = q_t*vL0 + r_t*vJ0.
// Only two dot products (L00, L01) are needed; the per-step update is scalar.
//
// R3 -> R4: recurrence no longer issues 4 scalar global stores per serial
// iteration (store-data register reuse forces a per-iteration s_waitcnt
// vmcnt -> store-completion latency ~300-900 cy on the critical path).
// Per-step scalars are staged in LDS (cheap ds_write), then bulk-copied to
// global with coalesced float4 stores by all 64 lanes after the loop.
// dot_partials and expand are byte-identical to R3 for clean attribution.

#define DIM 65536
#define STEPS 500
#define DIM4 (DIM / 4)            // 16384 float4 per vector
#define BLK_F4 2048               // float4 per expand block (8 blocks per step-row)
#define TOTAL_F4 (STEPS * DIM4)   // 8,192,000

typedef float vfloat4 __attribute__((ext_vector_type(4)));

__device__ constexpr float ALPHA0 = 1.0f;
__device__ constexpr float BETA_GAME = 0.2f;
__device__ constexpr float GAMMA_C = 0.5f;
__device__ constexpr float SIGMA = 10.0f;
__device__ constexpr float RHO = 28.0f;
__device__ constexpr float LORENZ_BETA = 8.0f / 3.0f;
__device__ constexpr float DT = 0.01f;
__device__ constexpr float EPS = 1e-8f;

// ws layout (floats):
//   [0..63]      per-block partial of vL0.vL0
//   [64..127]    per-block partial of vL0.vJ0
//   [128..627]   p[t]
//   [628..1127]  q[t]
//   [1128..1627] r[t]

__global__ __launch_bounds__(256) void dot_partials(const vfloat4* __restrict__ vL,
                                                    const vfloat4* __restrict__ vJ,
                                                    float* __restrict__ ws) {
    int tid = threadIdx.x;
    int idx = blockIdx.x * 256 + tid;          // 64 blocks * 256 = 16384 = DIM4
    vfloat4 a = vL[idx];
    vfloat4 b = vJ[idx];
    float sL  = a.x * a.x + a.y * a.y + a.z * a.z + a.w * a.w;
    float sLJ = a.x * b.x + a.y * b.y + a.z * b.z + a.w * b.w;
    #pragma unroll
    for (int off = 32; off > 0; off >>= 1) {
        sL  += __shfl_down(sL,  off, 64);
        sLJ += __shfl_down(sLJ, off, 64);
    }
    __shared__ float redL[4], redLJ[4];
    int wave = tid >> 6;
    if ((tid & 63) == 0) { redL[wave] = sL; redLJ[wave] = sLJ; }
    __syncthreads();
    if (tid == 0) {
        ws[blockIdx.x]      = redL[0] + redL[1] + redL[2] + redL[3];
        ws[64 + blockIdx.x] = redLJ[0] + redLJ[1] + redLJ[2] + redLJ[3];
    }
}

__global__ __launch_bounds__(64) void recurrence(float* __restrict__ ws,
                                                 float* __restrict__ outZ) {
    // SoA staging in LDS: [0..499]=p, [500..999]=q, [1000..1499]=r, [1500..1999]=z
    __shared__ __align__(16) float buf[4 * STEPS];   // 8 KB

    int tid = threadIdx.x;                      // one wave of 64
    float sL  = ws[tid];
    float sLJ = ws[64 + tid];
    #pragma unroll
    for (int off = 32; off > 0; off >>= 1) {
        sL  += __shfl_down(sL,  off, 64);
        sLJ += __shfl_down(sLJ, off, 64);
    }
    if (tid == 0) {
        const float L00 = sL;
        const float L01 = sLJ;
        float x = 1.f, y = 1.f, z = 1.f;
        float p = 1.f, q = 0.f, r = 1.f;
        for (int t = 0; t < STEPS; ++t) {
            float dx = SIGMA * (y - x);
            float dy = x * (RHO - z) - y;
            float dz = x * y - LORENZ_BETA * z;
            x += DT * dx;
            y += DT * dy;
            z += DT * dz;
            float alpha = ALPHA0 + GAMMA_C * z;
            float dot = p * (q * L00 + r * L01);
            float nsq = p * p * L00 + EPS;
            float c   = dot * __builtin_amdgcn_rcpf(nsq);
            float pn = p * (1.0f + DT * (alpha * (c - 1.0f) + BETA_GAME));
            float decay = 1.0f - DT * (alpha + BETA_GAME);
            float qn = q * decay + DT * p * (alpha * c + BETA_GAME);
            float rn = r * decay;
            p = pn; q = qn; r = rn;
            buf[t]             = p;   // LDS writes: no vmcnt stall on the
            buf[STEPS + t]     = q;   // serial chain (ds completion is fast)
            buf[2 * STEPS + t] = r;
            buf[3 * STEPS + t] = z;
        }
    }
    __syncthreads();

    // Bulk copy LDS -> global, coalesced float4 stores (125 f4 per array).
    const vfloat4* b4 = (const vfloat4*)buf;
    vfloat4* pq = (vfloat4*)(ws + 128);
    vfloat4* qq = (vfloat4*)(ws + 628);
    vfloat4* rq = (vfloat4*)(ws + 1128);
    vfloat4* zq = (vfloat4*)outZ;
    for (int i = tid; i < 125; i += 64) {
        pq[i] = b4[i];
        qq[i] = b4[125 + i];
        rq[i] = b4[250 + i];
        zq[i] = b4[375 + i];
    }
}

// 4000 blocks; each handles BLK_F4=2048 consecutive float4 of the flat
// [500 x 16384] float4 output. 2048 divides 16384 -> t is uniform per block.
__global__ __launch_bounds__(256) void expand(const vfloat4* __restrict__ vL,
                                              const vfloat4* __restrict__ vJ,
                                              const float* __restrict__ ws,
                                              vfloat4* __restrict__ outL,
                                              vfloat4* __restrict__ outJ) {
    int b = blockIdx.x;
    int t = b >> 3;                       // 8 blocks per step-row
    float p = ws[128 + t];
    float q = ws[628 + t];
    float r = ws[1128 + t];
    int  jbase = (b & 7) * BLK_F4;        // float4 offset within the vector
    long fbase = (long)b * BLK_F4;        // flat float4 offset in output
    int  tid = threadIdx.x;
    #pragma unroll
    for (int k = 0; k < 8; ++k) {
        int j = jbase + k * 256 + tid;    // lane-contiguous, coalesced
        vfloat4 a = vL[j];
        vfloat4 v = vJ[j];
        long f = fbase + k * 256 + tid;
        outL[f]            = p * a;
        outJ[f]            = q * a + r * v;
    }
}

extern "C" void kernel_launch(void* const* d_in, const int* in_sizes, int n_in,
                              void* d_out, int out_size, void* d_ws, size_t ws_size,
                              hipStream_t stream) {
    const vfloat4* vL = (const vfloat4*)d_in[0];
    const vfloat4* vJ = (const vfloat4*)d_in[1];
    float* out = (float*)d_out;
    float* ws  = (float*)d_ws;

    float*  outL = out;                                  // [500 * 65536]
    float*  outJ = out + (size_t)STEPS * DIM;            // [500 * 65536]
    float*  outZ = out + 2ull * STEPS * DIM;             // [500]

    dot_partials<<<64, 256, 0, stream>>>(vL, vJ, ws);
    recurrence<<<1, 64, 0, stream>>>(ws, outZ);
    expand<<<TOTAL_F4 / BLK_F4, 256, 0, stream>>>(vL, vJ, ws,
                                                  (vfloat4*)outL, (vfloat4*)outJ);
}

// Round 2
// 281.664 us; speedup vs baseline: 1.1055x; 1.0975x over previous
//
#include <hip/hip_runtime.h>

// CognitiveLorenzField: 500-step scan over DIM=65536 vectors.
// Exact 2D-subspace reduction: vL_t = p_t*vL0, vJ_t = q_t*vL0 + r_t*vJ0.
// Only two dot products (L00, L01) are needed; the per-step update is scalar.
//
// R4 -> R5: the standalone 1-block recurrence kernel (~150 us: a full-GPU
// serialization point running a serial chain on an idle, unboosted chip) is
// eliminated. Each expand block redundantly (a) reduces the 64 dot partials
// with the same deterministic wave-shuffle order, (b) runs the scalar
// recurrence up to its own t on wave 0 while waves 1-3 wait, (c) broadcasts
// p,q,r via LDS, then streams its output slice. The serial compute now runs
// at full occupancy and overlaps with other blocks' streaming writes.
// Block NBLK-1 (t=499) also stages z[t] in LDS and bulk-writes outZ.

#define DIM 65536
#define STEPS 500
#define DIM4 (DIM / 4)            // 16384 float4 per vector
#define BLK_F4 4096               // float4 per expand block (4 blocks per step-row)
#define NBLK (STEPS * 4)          // 2000 blocks, one residency round

typedef float vfloat4 __attribute__((ext_vector_type(4)));

__device__ constexpr float ALPHA0 = 1.0f;
__device__ constexpr float BETA_GAME = 0.2f;
__device__ constexpr float GAMMA_C = 0.5f;
__device__ constexpr float SIGMA = 10.0f;
__device__ constexpr float RHO = 28.0f;
__device__ constexpr float LORENZ_BETA = 8.0f / 3.0f;
__device__ constexpr float DT = 0.01f;
__device__ constexpr float EPS = 1e-8f;

// ws layout (floats):
//   [0..63]      per-block partial of vL0.vL0
//   [64..127]    per-block partial of vL0.vJ0

__global__ __launch_bounds__(256) void dot_partials(const vfloat4* __restrict__ vL,
                                                    const vfloat4* __restrict__ vJ,
                                                    float* __restrict__ ws) {
    int tid = threadIdx.x;
    int idx = blockIdx.x * 256 + tid;          // 64 blocks * 256 = 16384 = DIM4
    vfloat4 a = vL[idx];
    vfloat4 b = vJ[idx];
    float sL  = a.x * a.x + a.y * a.y + a.z * a.z + a.w * a.w;
    float sLJ = a.x * b.x + a.y * b.y + a.z * b.z + a.w * b.w;
    #pragma unroll
    for (int off = 32; off > 0; off >>= 1) {
        sL  += __shfl_down(sL,  off, 64);
        sLJ += __shfl_down(sLJ, off, 64);
    }
    __shared__ float redL[4], redLJ[4];
    int wave = tid >> 6;
    if ((tid & 63) == 0) { redL[wave] = sL; redLJ[wave] = sLJ; }
    __syncthreads();
    if (tid == 0) {
        ws[blockIdx.x]      = redL[0] + redL[1] + redL[2] + redL[3];
        ws[64 + blockIdx.x] = redLJ[0] + redLJ[1] + redLJ[2] + redLJ[3];
    }
}

// 2000 blocks; block b owns float4 range [b*4096, (b+1)*4096) of the flat
// [500 x 16384] float4 output => t = b>>2 is uniform per block.
__global__ __launch_bounds__(256) void expand_fused(const vfloat4* __restrict__ vL,
                                                    const vfloat4* __restrict__ vJ,
                                                    const float* __restrict__ ws,
                                                    vfloat4* __restrict__ outL,
                                                    vfloat4* __restrict__ outJ,
                                                    float* __restrict__ outZ) {
    __shared__ float sh_p, sh_q, sh_r;
    __shared__ __align__(16) float zbuf[STEPS];

    const int  b   = blockIdx.x;
    const int  myT = b >> 2;                  // which step this block expands
    const int  tid = threadIdx.x;
    const bool zW  = (b == NBLK - 1);         // myT == 499: stages z trajectory

    if (tid < 64) {                           // wave 0 only: recurrence
        // Deterministic 64->1 reduction of the dot partials (same shuffle
        // order as the old recurrence kernel -> bitwise-identical L00/L01).
        float sL  = ws[tid];
        float sLJ = ws[64 + tid];
        #pragma unroll
        for (int off = 32; off > 0; off >>= 1) {
            sL  += __shfl_down(sL,  off, 64);
            sLJ += __shfl_down(sLJ, off, 64);
        }
        const float L00 = __shfl(sL, 0, 64);
        const float L01 = __shfl(sLJ, 0, 64);

        float x = 1.f, y = 1.f, z = 1.f;
        float p = 1.f, q = 0.f, r = 1.f;
        for (int t = 0; t <= myT; ++t) {
            float dx = SIGMA * (y - x);
            float dy = x * (RHO - z) - y;
            float dz = x * y - LORENZ_BETA * z;
            x += DT * dx;
            y += DT * dy;
            z += DT * dz;
            float alpha = ALPHA0 + GAMMA_C * z;
            float dot = p * (q * L00 + r * L01);
            float nsq = p * p * L00 + EPS;
            float c   = dot * __builtin_amdgcn_rcpf(nsq);
            float pn = p * (1.0f + DT * (alpha * (c - 1.0f) + BETA_GAME));
            float decay = 1.0f - DT * (alpha + BETA_GAME);
            float qn = q * decay + DT * p * (alpha * c + BETA_GAME);
            float rn = r * decay;
            p = pn; q = qn; r = rn;
            if (zW && tid == 0) zbuf[t] = z;  // LDS stage; block 1999 only
        }
        if (tid == 0) { sh_p = p; sh_q = q; sh_r = r; }
    }
    __syncthreads();
    const float p = sh_p, q = sh_q, r = sh_r;

    if (zW) {                                 // bulk-write z trajectory
        const vfloat4* zb4 = (const vfloat4*)zbuf;
        vfloat4* zq = (vfloat4*)outZ;
        if (tid < STEPS / 4) zq[tid] = zb4[tid];
    }

    const int  jbase = (b & 3) * BLK_F4;      // float4 offset within vector
    const long fbase = (long)b * BLK_F4;      // flat float4 offset in output
    #pragma unroll 4
    for (int k = 0; k < 16; ++k) {
        int j = jbase + k * 256 + tid;        // lane-contiguous, coalesced
        vfloat4 a = vL[j];
        vfloat4 v = vJ[j];
        long f = fbase + k * 256 + tid;
        outL[f] = p * a;
        outJ[f] = q * a + r * v;
    }
}

extern "C" void kernel_launch(void* const* d_in, const int* in_sizes, int n_in,
                              void* d_out, int out_size, void* d_ws, size_t ws_size,
                              hipStream_t stream) {
    const vfloat4* vL = (const vfloat4*)d_in[0];
    const vfloat4* vJ = (const vfloat4*)d_in[1];
    float* out = (float*)d_out;
    float* ws  = (float*)d_ws;

    float* outL = out;                                   // [500 * 65536]
    float* outJ = out + (size_t)STEPS * DIM;             // [500 * 65536]
    float* outZ = out + 2ull * STEPS * DIM;              // [500]

    dot_partials<<<64, 256, 0, stream>>>(vL, vJ, ws);
    expand_fused<<<NBLK, 256, 0, stream>>>(vL, vJ, ws,
                                           (vfloat4*)outL, (vfloat4*)outJ, outZ);
}

// Round 3
// 264.751 us; speedup vs baseline: 1.1762x; 1.0639x over previous
//
#include <hip/hip_runtime.h>

// CognitiveLorenzField: 500-step scan over DIM=65536 vectors.
// Exact 2D-subspace reduction: vL_t = p_t*vL0, vJ_t = q_t*vL0 + r_t*vJ0.
//
// R5 -> R6: expand restructured from "1 t-step per block, re-load inputs
// every store" (load->FMA->store chains; ~2.3 TB/s) to "T=10 t-steps per
// block, input slice register-cached once" (fill-like pure store stream).
// Per block: issue 32 slice loads, wave 0 runs the recurrence to this
// block's t-range (identical float ops -> bitwise-identical p,q,r), stage
// p/q/r (+z for one block) in LDS, one barrier, then 80 dependency-free
// dwordx4 stores per thread. L2 read traffic drops 262 MB -> 26 MB.

#define DIM 65536
#define STEPS 500
#define DIM4 (DIM / 4)            // 16384 float4 per vector per step
#define T_GRP 10                  // time steps per block
#define NTG (STEPS / T_GRP)       // 50 t-groups
#define JBLK 16                   // j-slices per step-row
#define SLICE_F4 1024             // float4 per j-slice (4 per thread per vector)
#define NBLK (NTG * JBLK)         // 800 blocks (= 8 XCDs * 100), all co-resident

typedef float vfloat4 __attribute__((ext_vector_type(4)));

__device__ constexpr float ALPHA0 = 1.0f;
__device__ constexpr float BETA_GAME = 0.2f;
__device__ constexpr float GAMMA_C = 0.5f;
__device__ constexpr float SIGMA = 10.0f;
__device__ constexpr float RHO = 28.0f;
__device__ constexpr float LORENZ_BETA = 8.0f / 3.0f;
__device__ constexpr float DT = 0.01f;
__device__ constexpr float EPS = 1e-8f;

// ws layout (floats):
//   [0..63]      per-block partial of vL0.vL0
//   [64..127]    per-block partial of vL0.vJ0

__global__ __launch_bounds__(256) void dot_partials(const vfloat4* __restrict__ vL,
                                                    const vfloat4* __restrict__ vJ,
                                                    float* __restrict__ ws) {
    int tid = threadIdx.x;
    int idx = blockIdx.x * 256 + tid;          // 64 blocks * 256 = 16384 = DIM4
    vfloat4 a = vL[idx];
    vfloat4 b = vJ[idx];
    float sL  = a.x * a.x + a.y * a.y + a.z * a.z + a.w * a.w;
    float sLJ = a.x * b.x + a.y * b.y + a.z * b.z + a.w * b.w;
    #pragma unroll
    for (int off = 32; off > 0; off >>= 1) {
        sL  += __shfl_down(sL,  off, 64);
        sLJ += __shfl_down(sLJ, off, 64);
    }
    __shared__ float redL[4], redLJ[4];
    int wave = tid >> 6;
    if ((tid & 63) == 0) { redL[wave] = sL; redLJ[wave] = sLJ; }
    __syncthreads();
    if (tid == 0) {
        ws[blockIdx.x]      = redL[0] + redL[1] + redL[2] + redL[3];
        ws[64 + blockIdx.x] = redLJ[0] + redLJ[1] + redLJ[2] + redLJ[3];
    }
}

// 800 blocks: b = tg*16 + jb. Block owns j-slice [jb*1024, jb*1024+1024) of
// the 16384-f4 step-row, for 10 consecutive steps t in [tg*10, tg*10+10).
__global__ __launch_bounds__(256) void expand_fused(const vfloat4* __restrict__ vL,
                                                    const vfloat4* __restrict__ vJ,
                                                    const float* __restrict__ ws,
                                                    vfloat4* __restrict__ outL,
                                                    vfloat4* __restrict__ outJ,
                                                    float* __restrict__ outZ) {
    __shared__ float pb[T_GRP], qb[T_GRP], rb[T_GRP];
    __shared__ __align__(16) float zbuf[STEPS];

    const int  b   = blockIdx.x;
    const int  jb  = b & (JBLK - 1);
    const int  tg  = b >> 4;
    const int  t0  = tg * T_GRP;
    const int  tid = threadIdx.x;
    const bool zW  = (tg == NTG - 1) && (jb == 0);   // passes through all 500 z

    // Issue the slice loads first; latency hides under the recurrence.
    const int jbase = jb * SLICE_F4;
    vfloat4 aL[4], aJ[4];
    #pragma unroll
    for (int k = 0; k < 4; ++k) {
        aL[k] = vL[jbase + k * 256 + tid];
        aJ[k] = vJ[jbase + k * 256 + tid];
    }

    if (tid < 64) {                           // wave 0 only: recurrence
        // Deterministic 64->1 reduction (same order as before -> same bits).
        float sL  = ws[tid];
        float sLJ = ws[64 + tid];
        #pragma unroll
        for (int off = 32; off > 0; off >>= 1) {
            sL  += __shfl_down(sL,  off, 64);
            sLJ += __shfl_down(sLJ, off, 64);
        }
        const float L00 = __shfl(sL, 0, 64);
        const float L01 = __shfl(sLJ, 0, 64);

        float x = 1.f, y = 1.f, z = 1.f;
        float p = 1.f, q = 0.f, r = 1.f;
        // Prologue: steps [0, t0)
        for (int t = 0; t < t0; ++t) {
            float dx = SIGMA * (y - x);
            float dy = x * (RHO - z) - y;
            float dz = x * y - LORENZ_BETA * z;
            x += DT * dx;
            y += DT * dy;
            z += DT * dz;
            float alpha = ALPHA0 + GAMMA_C * z;
            float dot = p * (q * L00 + r * L01);
            float nsq = p * p * L00 + EPS;
            float c   = dot * __builtin_amdgcn_rcpf(nsq);
            float pn = p * (1.0f + DT * (alpha * (c - 1.0f) + BETA_GAME));
            float decay = 1.0f - DT * (alpha + BETA_GAME);
            float qn = q * decay + DT * p * (alpha * c + BETA_GAME);
            float rn = r * decay;
            p = pn; q = qn; r = rn;
            if (zW && tid == 0) zbuf[t] = z;
        }
        // Main: steps [t0, t0+T_GRP), stage coefficients in LDS.
        for (int tt = 0; tt < T_GRP; ++tt) {
            float dx = SIGMA * (y - x);
            float dy = x * (RHO - z) - y;
            float dz = x * y - LORENZ_BETA * z;
            x += DT * dx;
            y += DT * dy;
            z += DT * dz;
            float alpha = ALPHA0 + GAMMA_C * z;
            float dot = p * (q * L00 + r * L01);
            float nsq = p * p * L00 + EPS;
            float c   = dot * __builtin_amdgcn_rcpf(nsq);
            float pn = p * (1.0f + DT * (alpha * (c - 1.0f) + BETA_GAME));
            float decay = 1.0f - DT * (alpha + BETA_GAME);
            float qn = q * decay + DT * p * (alpha * c + BETA_GAME);
            float rn = r * decay;
            p = pn; q = qn; r = rn;
            if (tid == 0) {
                pb[tt] = p; qb[tt] = q; rb[tt] = r;
                if (zW) zbuf[t0 + tt] = z;
            }
        }
    }
    __syncthreads();

    if (zW) {                                 // bulk-write z trajectory
        if (tid < STEPS / 4)
            ((vfloat4*)outZ)[tid] = ((const vfloat4*)zbuf)[tid];
    }

    // Pure store stream: 80 dwordx4 stores per thread, no load dependencies.
    long base = (long)t0 * DIM4 + jbase;      // flat f4 index of (t0, jbase)
    for (int tt = 0; tt < T_GRP; ++tt) {
        const float p = pb[tt], q = qb[tt], r = rb[tt];
        #pragma unroll
        for (int k = 0; k < 4; ++k) {
            long f = base + k * 256 + tid;
            outL[f] = p * aL[k];
            outJ[f] = q * aL[k] + r * aJ[k];
        }
        base += DIM4;
    }
}

extern "C" void kernel_launch(void* const* d_in, const int* in_sizes, int n_in,
                              void* d_out, int out_size, void* d_ws, size_t ws_size,
                              hipStream_t stream) {
    const vfloat4* vL = (const vfloat4*)d_in[0];
    const vfloat4* vJ = (const vfloat4*)d_in[1];
    float* out = (float*)d_out;
    float* ws  = (float*)d_ws;

    float* outL = out;                                   // [500 * 65536]
    float* outJ = out + (size_t)STEPS * DIM;             // [500 * 65536]
    float* outZ = out + 2ull * STEPS * DIM;              // [500]

    dot_partials<<<64, 256, 0, stream>>>(vL, vJ, ws);
    expand_fused<<<NBLK, 256, 0, stream>>>(vL, vJ, ws,
                                           (vfloat4*)outL, (vfloat4*)outJ, outZ);
}